// Round 8
// baseline (1133.033 us; speedup 1.0000x reference)
//
#include <hip/hip_runtime.h>
#include <hip/hip_bf16.h>

typedef _Float16 f16;
typedef _Float16 f16x8 __attribute__((ext_vector_type(8)));
typedef float    f32x4 __attribute__((ext_vector_type(4)));
typedef float    f32x8 __attribute__((ext_vector_type(8)));

__device__ __forceinline__ float silu_f(float x) {
    return x * __builtin_amdgcn_rcpf(1.0f + __expf(-x));
}

// f16 transcendentals via asm (types routed through short for constraint safety)
__device__ __forceinline__ f16 exp2h(f16 x) {
    short r, xs = __builtin_bit_cast(short, x);
    asm("v_exp_f16 %0, %1" : "=v"(r) : "v"(xs));
    return __builtin_bit_cast(f16, r);
}
__device__ __forceinline__ f16 rcph(f16 x) {
    short r, xs = __builtin_bit_cast(short, x);
    asm("v_rcp_f16 %0, %1" : "=v"(r) : "v"(xs));
    return __builtin_bit_cast(f16, r);
}
// packed-f16 silu: x * rcp(1 + exp2(-log2e * x)); tails exact via inf/0
__device__ __forceinline__ f16x8 silu_h8(f16x8 x) {
    f16x8 t = x * (f16)(-1.442695040f);   // v_pk_mul_f16 x4
    f16x8 e;
#pragma unroll
    for (int j = 0; j < 8; j++) e[j] = exp2h(t[j]);
    f16x8 d = e + (f16)1.0f;              // v_pk_add_f16 x4
    f16x8 r;
#pragma unroll
    for (int j = 0; j < 8; j++) r[j] = rcph(d[j]);
    return x * r;                          // v_pk_mul_f16 x4
}

// async 16B/lane global->LDS DMA
__device__ __forceinline__ void load_lds16(const f16* g, f16* l) {
    __builtin_amdgcn_global_load_lds(
        (const __attribute__((address_space(1))) void*)g,
        (__attribute__((address_space(3))) void*)l, 16, 0, 0);
}

// ---------------------------------------------------------------------------
// Weight prep: B1T[l][256][64], W2T[l][128][128], W3T[l][64][128], w1c f16
// ---------------------------------------------------------------------------
__global__ void prep_kernel(const float* __restrict__ W1, const float* __restrict__ W2,
                            const float* __restrict__ W3, f16* __restrict__ B1T,
                            f16* __restrict__ W2T, f16* __restrict__ W3T,
                            f16* __restrict__ w1c, int L, int total) {
    int idx = blockIdx.x * 256 + threadIdx.x;
    if (idx >= total) return;
    const int per = 16384 + 16384 + 8192 + 128;
    int l = idx / per, r = idx % per;
    const float* W1l = W1 + (size_t)l * 126 * 128;
    if (r < 16384) {
        int c = r >> 6, k = r & 63;
        float v;
        if (c < 128) v = W1l[k * 128 + c];
        else v = (k >= 3) ? W1l[(64 + k - 3) * 128 + (c - 128)] : 0.0f;
        B1T[(size_t)l * 16384 + r] = (f16)v;
    } else if (r < 32768) {
        int q = r - 16384, n = q >> 7, k = q & 127;
        W2T[(size_t)l * 16384 + q] = (f16)W2[(size_t)l * 16384 + k * 128 + n];
    } else if (r < 40960) {
        int q = r - 32768, n = q >> 7, k = q & 127;
        W3T[(size_t)l * 8192 + q] = (f16)W3[(size_t)l * 8192 + k * 64 + n];
    } else {
        int c = r - 40960;
        w1c[l * 128 + c] = (f16)W1l[125 * 128 + c];
    }
}

// ---------------------------------------------------------------------------
// CSR build: histogram, 2-level scan, counting-sort scatter (int2 payload)
// ---------------------------------------------------------------------------
__global__ void hist_kernel(const int* __restrict__ ei, int* __restrict__ deg, int E) {
    int i = blockIdx.x * 256 + threadIdx.x;
    if (i < E) atomicAdd(&deg[ei[E + i]], 1);
}

__global__ void scan_part(const int* __restrict__ deg, int* __restrict__ bsum, int N) {
    __shared__ int red[256];
    int t = threadIdx.x;
    int i = blockIdx.x * 256 + t;
    red[t] = (i < N) ? deg[i] : 0;
    __syncthreads();
    for (int s = 128; s > 0; s >>= 1) {
        if (t < s) red[t] += red[t + s];
        __syncthreads();
    }
    if (t == 0) bsum[blockIdx.x] = red[0];
}

__global__ void scan_mid(const int* __restrict__ bsum, int* __restrict__ boff, int nb) {
    __shared__ int sm[512];
    int t = threadIdx.x;
    int v = (t < nb) ? bsum[t] : 0;
    sm[t] = v;
    __syncthreads();
    for (int off = 1; off < 512; off <<= 1) {
        int a = (t >= off) ? sm[t - off] : 0;
        __syncthreads();
        sm[t] += a;
        __syncthreads();
    }
    if (t < nb) boff[t] = sm[t] - v;
}

__global__ void scan_final(const int* __restrict__ deg, const int* __restrict__ boff,
                           int* __restrict__ row_start, int N) {
    __shared__ int sm[256];
    int t = threadIdx.x;
    int i = blockIdx.x * 256 + t;
    int v = (i < N) ? deg[i] : 0;
    sm[t] = v;
    __syncthreads();
    for (int off = 1; off < 256; off <<= 1) {
        int a = (t >= off) ? sm[t - off] : 0;
        __syncthreads();
        sm[t] += a;
        __syncthreads();
    }
    if (i < N) row_start[i] = boff[blockIdx.x] + sm[t] - v;
}

__global__ void scatter_kernel(const int* __restrict__ ei, const int* __restrict__ row_start,
                               int* __restrict__ cursor, int2* __restrict__ sd, int E) {
    int i = blockIdx.x * 256 + threadIdx.x;
    if (i < E) {
        int d = ei[E + i];
        int p = row_start[d] + atomicAdd(&cursor[d], 1);
        sd[p] = make_int2(ei[i], d);   // one 8B store (same line) vs two 4B
    }
}

// ---------------------------------------------------------------------------
// Node kernel: PQ[n][0:128] = x@W1a + b1 ; PQ[n][128:256] = x[3:]@W1b ; C=xyz
// ---------------------------------------------------------------------------
__global__ __launch_bounds__(256, 3) void node_kernel(
    const float* __restrict__ x, const f16* __restrict__ B1T,
    const float* __restrict__ b1, f16* __restrict__ PQ,
    float4* __restrict__ C, int N, int ntiles) {
    __shared__ f16 b1t[256 * 72];
    const int tid = threadIdx.x;
    const int w = tid >> 6, lane = tid & 63, lm = lane & 15, kg = lane >> 4;

    for (int i = tid; i < 256 * 64; i += 256)
        b1t[(i >> 6) * 72 + (i & 63)] = B1T[i];
    __syncthreads();

    for (int tile = blockIdx.x; tile < ntiles; tile += gridDim.x) {
        const int base = tile * 64;
        int ar = base + w * 16 + lm;
        if (ar >= N) ar = N - 1;

        f16x8 afrag[2];
#pragma unroll
        for (int ks = 0; ks < 2; ks++) {
            f32x8 v = *(const f32x8*)(x + (size_t)ar * 64 + ks * 32 + kg * 8);
            f16x8 h;
#pragma unroll
            for (int j = 0; j < 8; j++) h[j] = (f16)v[j];
            afrag[ks] = h;
        }

        f32x4 acc[16];
#pragma unroll
        for (int nb = 0; nb < 16; nb++) acc[nb] = (f32x4){0.f, 0.f, 0.f, 0.f};
#pragma unroll
        for (int ks = 0; ks < 2; ks++)
#pragma unroll
            for (int nb = 0; nb < 16; nb++) {
                f16x8 b = *(const f16x8*)&b1t[(nb * 16 + lm) * 72 + ks * 32 + kg * 8];
                acc[nb] = __builtin_amdgcn_mfma_f32_16x16x32_f16(afrag[ks], b, acc[nb], 0, 0, 0);
            }

#pragma unroll
        for (int nb = 0; nb < 16; nb++) {
            int col = nb * 16 + lm;
            float bias = (col < 128) ? b1[col] : 0.0f;
#pragma unroll
            for (int reg = 0; reg < 4; reg++) {
                int orow = base + w * 16 + kg * 4 + reg;
                if (orow < N) PQ[(size_t)orow * 256 + col] = (f16)(acc[nb][reg] + bias);
            }
        }
        if (tid < 64) {
            int n = base + tid;
            if (n < N) {
                const float* xr = x + (size_t)n * 64;
                C[n] = make_float4(xr[0], xr[1], xr[2], 0.0f);
            }
        }
    }
}

// ---------------------------------------------------------------------------
// Edge kernel v8 (R5 structure): wave-independent 16-edge tiles.
//   p|q both DMA-staged (32KB); W2T + W3T in LDS (32+8KB, XOR-swizzled);
//   packed-f16 h1 silu (v_exp_f16/v_rcp_f16); deferred-epilogue atomics;
//   precise wait: pending after DMA = sd(1) + C(2) -> vmcnt(3).
// LDS 32+32+8+4.5 = 76.5KB -> 2 blocks/CU.
// ---------------------------------------------------------------------------
__global__ __launch_bounds__(256, 2) void edge_kernel(
    const f16* __restrict__ PQ, const float4* __restrict__ C,
    const int2* __restrict__ sd,
    const f16* __restrict__ W2T, const f16* __restrict__ W3T,
    const f16* __restrict__ w1c, const float* __restrict__ b2,
    const float* __restrict__ b3, float* __restrict__ xout,
    int E, int wtiles) {
    __shared__ f16 w2t[128 * 128];       // 32KB XOR-swizzled
    __shared__ f16 stage[4 * 4096];      // 32KB per-wave p|q
    __shared__ f16 w3t[64 * 128];        // 8KB XOR-swizzled
    __shared__ f16 tb[4 * 576];          // 4.5KB per-wave transpose slices

    const int tid = threadIdx.x;
    const int w = tid >> 6, lane = tid & 63, lm = lane & 15, kg = lane >> 4;
    const int e4 = lane >> 2, c4 = lane & 3;

    for (int i = tid; i < 128 * 128; i += 256) {
        int n = i >> 7, k = i & 127;
        w2t[n * 128 + (((k >> 3) ^ (n & 15)) << 3) + (k & 7)] = W2T[i];
    }
    for (int i = tid; i < 64 * 128; i += 256) {
        int n = i >> 7, k = i & 127;
        w3t[n * 128 + (((k >> 3) ^ (n & 15)) << 3) + (k & 7)] = W3T[i];
    }

    // loop-invariant hoists
    f16x8 wvh[4];
#pragma unroll
    for (int ks = 0; ks < 4; ks++) wvh[ks] = *(const f16x8*)(w1c + ks * 32 + kg * 8);
    float bias2[8], bias3[4];
#pragma unroll
    for (int nb = 0; nb < 8; nb++) bias2[nb] = b2[nb * 16 + lm];
#pragma unroll
    for (int nb = 0; nb < 4; nb++) bias3[nb] = b3[nb * 16 + lm];
    __syncthreads();   // weights staged; no barriers after this

    f16* sw = stage + w * 4096;          // p at 0, q at 2048
    f16* tq = tb + w * 576;
    const int nwaves = gridDim.x * 4;
    const int r0 = kg * 4;
    const int l1i = (lane + 16) & 63, l2i = (lane + 32) & 63, l3i = (lane + 48) & 63;

    // ---- prologue ----
    int t = blockIdx.x * 4 + w;
    if (t >= wtiles) return;
    int e0 = t * 16 + lm;
    int erc = min(e0, E - 1);
    int2 sd0 = sd[erc];
    int scl = sd0.x, dcl = sd0.y;
    int dsen_cur = (e0 < E) ? dcl : -1;
    {   // DMA(t)
        int de = __shfl(dcl, e4), se = __shfl(scl, e4);
        const f16* gp = PQ + (size_t)de * 256 + c4 * 8;
        const f16* gq = PQ + (size_t)se * 256 + 128 + c4 * 8;
#pragma unroll
        for (int j = 0; j < 4; j++) load_lds16(gp + j * 32, sw + j * 512 + lane * 8);
#pragma unroll
        for (int j = 0; j < 4; j++) load_lds16(gq + j * 32, sw + 2048 + j * 512 + lane * 8);
    }
    int e1 = (t + nwaves) * 16 + lm;
    int erc1 = min(max(e1, 0), E - 1);
    int2 sdn = sd[erc1];
    int s_nx = sdn.x, d_nx = sdn.y;
    int e_nx_ok = (e1 < E) ? 1 : 0;
    float4 cs = C[scl], cd = C[dcl];

    f32x4 acc2p[4];
#pragma unroll
    for (int nb2 = 0; nb2 < 4; nb2++) acc2p[nb2] = (f32x4){0.f, 0.f, 0.f, 0.f};
    int dsen_prev = -1;

    while (true) {
        const int tn = t + nwaves;

        // ---- 1. stage(t) ready: drain atomics+DMA, leave sd+C (3) ----
        asm volatile("s_waitcnt vmcnt(3)" ::: "memory");

        float dx = cs.x - cd.x, dy = cs.y - cd.y, dz = cs.z - cd.z;
        float dist2 = dx * dx + dy * dy + dz * dz;
        f16 d2h = (f16)dist2;

        // ---- 2. h1: packed f16 (pk_add/pk_fma + f16 silu) ----
        f16x8 afrag[4];
#pragma unroll
        for (int ks = 0; ks < 4; ks++) {
            f16x8 p = *(const f16x8*)&sw[ks * 512 + lm * 32 + kg * 8];
            f16x8 q = *(const f16x8*)&sw[2048 + ks * 512 + lm * 32 + kg * 8];
            f16x8 xv = p + q + d2h * wvh[ks];
            afrag[ks] = silu_h8(xv);
        }

        // ---- GEMM1: h1 @ W2 ----
        f32x4 acc1[8];
#pragma unroll
        for (int nb = 0; nb < 8; nb++) acc1[nb] = (f32x4){0.f, 0.f, 0.f, 0.f};
#pragma unroll
        for (int ks = 0; ks < 4; ks++)
#pragma unroll
            for (int nb = 0; nb < 8; nb++) {
                int n = nb * 16 + lm;
                f16x8 b = *(const f16x8*)&w2t[n * 128 + (((ks * 4 + kg) ^ (n & 15)) << 3)];
                acc1[nb] = __builtin_amdgcn_mfma_f32_16x16x32_f16(afrag[ks], b, acc1[nb], 0, 0, 0);
            }

        // ---- 3. deferred epilogue for PREVIOUS tile (atomics precede DMA) ----
        {
            const int dr0 = __shfl(dsen_prev, r0);
            const int dr1 = __shfl(dsen_prev, r0 + 1);
            const int dr2 = __shfl(dsen_prev, r0 + 2);
            const int dr3 = __shfl(dsen_prev, r0 + 3);
            int prevv = __shfl(dsen_prev, (r0 - 1) & 63);
            if (kg == 0) prevv = -1234567;

            const bool e01 = dr0 == dr1, e12 = dr1 == dr2, e23 = dr2 == dr3;
            const bool c01 = e01, c02 = e01 && e12, c03 = c02 && e23;
            const bool c12 = e12, c13 = e12 && e23;
            const int fullI = c03 ? 1 : 0;

            const int tgt = dr3;
            const int dr0_1 = __shfl(dr0, l1i), fu1 = __shfl(fullI, l1i);
            const int dr0_2 = __shfl(dr0, l2i), fu2 = __shfl(fullI, l2i);
            const int dr0_3 = __shfl(dr0, l3i);
            const bool take1 = (kg <= 2) && (dr0_1 == tgt);
            const bool take2 = take1 && fu1 && (kg <= 1) && (dr0_2 == tgt);
            const bool take3 = take2 && fu2 && (kg == 0) && (dr0_3 == tgt);

            const bool h0 = (dr0 != prevv) && (dr0 >= 0);
            const bool h1f = (!e01) && (dr1 >= 0);
            const bool h2f = (!e12) && (dr2 >= 0);
            const bool h3f = (!e23) && (dr3 >= 0);

            float t0v[4], t1v[4], t2v[4], t3v[4];
#pragma unroll
            for (int nb2 = 0; nb2 < 4; nb2++) {
                const float bias = bias3[nb2];
                const float v0 = silu_f(acc2p[nb2][0] + bias);
                const float v1 = silu_f(acc2p[nb2][1] + bias);
                const float v2 = silu_f(acc2p[nb2][2] + bias);
                const float v3 = silu_f(acc2p[nb2][3] + bias);
                float lead = v0 + (c01 ? v1 : 0.f) + (c02 ? v2 : 0.f) + (c03 ? v3 : 0.f);
                float ext = 0.f;
                const float le1 = __shfl(lead, l1i);
                const float le2 = __shfl(lead, l2i);
                const float le3 = __shfl(lead, l3i);
                if (take1) ext += le1;
                if (take2) ext += le2;
                if (take3) ext += le3;
                t0v[nb2] = lead + (c03 ? ext : 0.f);
                t1v[nb2] = v1 + (c12 ? v2 : 0.f) + (c13 ? (v3 + ext) : 0.f);
                t2v[nb2] = v2 + (e23 ? (v3 + ext) : 0.f);
                t3v[nb2] = v3 + ext;
            }
            if (h0) {
                float* p = xout + (size_t)dr0 * 64 + lm;
#pragma unroll
                for (int nb2 = 0; nb2 < 4; nb2++) atomicAdd(p + nb2 * 16, t0v[nb2]);
            }
            if (h1f) {
                float* p = xout + (size_t)dr1 * 64 + lm;
#pragma unroll
                for (int nb2 = 0; nb2 < 4; nb2++) atomicAdd(p + nb2 * 16, t1v[nb2]);
            }
            if (h2f) {
                float* p = xout + (size_t)dr2 * 64 + lm;
#pragma unroll
                for (int nb2 = 0; nb2 < 4; nb2++) atomicAdd(p + nb2 * 16, t2v[nb2]);
            }
            if (h3f) {
                float* p = xout + (size_t)dr3 * 64 + lm;
#pragma unroll
                for (int nb2 = 0; nb2 < 4; nb2++) atomicAdd(p + nb2 * 16, t3v[nb2]);
            }
        }

        // ---- 4. DMA(t+nw) into stage ----
        int dsen_nx = e_nx_ok ? d_nx : -1;
        if (tn < wtiles) {
            int de = __shfl(d_nx, e4), se = __shfl(s_nx, e4);
            const f16* gp = PQ + (size_t)de * 256 + c4 * 8;
            const f16* gq = PQ + (size_t)se * 256 + 128 + c4 * 8;
#pragma unroll
            for (int j = 0; j < 4; j++) load_lds16(gp + j * 32, sw + j * 512 + lane * 8);
#pragma unroll
            for (int j = 0; j < 4; j++) load_lds16(gq + j * 32, sw + 2048 + j * 512 + lane * 8);
        }

        // ---- 5. sd(t+2nw) and C(t+nw): the 3 left pending ----
        int e2 = (tn + nwaves) * 16 + lm;
        int erc2 = min(max(e2, 0), E - 1);
        int2 sd2 = sd[erc2];
        int e_nx2_ok = (e2 < E) ? 1 : 0;
        float4 cs2 = C[s_nx], cd2 = C[d_nx];

        // ---- 6. GEMM2 in 4 k-quarters (w3t in LDS now) ----
        f32x4 acc2[4];
#pragma unroll
        for (int nb2 = 0; nb2 < 4; nb2++) acc2[nb2] = (f32x4){0.f, 0.f, 0.f, 0.f};
#pragma unroll
        for (int kq = 0; kq < 4; kq++) {
#pragma unroll
            for (int nn = 0; nn < 2; nn++) {
                int nb = kq * 2 + nn;
#pragma unroll
                for (int reg = 0; reg < 4; reg++)
                    tq[(kg * 4 + reg) * 36 + nn * 16 + lm] =
                        (f16)silu_f(acc1[nb][reg] + bias2[nb]);
            }
            f16x8 a2 = *(const f16x8*)&tq[lm * 36 + kg * 8];
#pragma unroll
            for (int nb2 = 0; nb2 < 4; nb2++) {
                int n = nb2 * 16 + lm;
                f16x8 b = *(const f16x8*)&w3t[n * 128 + (((kq * 4 + kg) ^ (n & 15)) << 3)];
                acc2[nb2] = __builtin_amdgcn_mfma_f32_16x16x32_f16(a2, b, acc2[nb2], 0, 0, 0);
            }
        }

        // ---- 7. rotate pipeline state ----
#pragma unroll
        for (int nb2 = 0; nb2 < 4; nb2++) acc2p[nb2] = acc2[nb2];
        dsen_prev = dsen_cur;
        dsen_cur = dsen_nx;
        s_nx = sd2.x; d_nx = sd2.y; e_nx_ok = e_nx2_ok;
        cs = cs2; cd = cd2;
        t = tn;
        if (t >= wtiles) break;
    }

    // ---- final deferred epilogue ----
    {
        const int dr0 = __shfl(dsen_prev, r0);
        const int dr1 = __shfl(dsen_prev, r0 + 1);
        const int dr2 = __shfl(dsen_prev, r0 + 2);
        const int dr3 = __shfl(dsen_prev, r0 + 3);
        int prevv = __shfl(dsen_prev, (r0 - 1) & 63);
        if (kg == 0) prevv = -1234567;

        const bool e01 = dr0 == dr1, e12 = dr1 == dr2, e23 = dr2 == dr3;
        const bool c01 = e01, c02 = e01 && e12, c03 = c02 && e23;
        const bool c12 = e12, c13 = e12 && e23;
        const int fullI = c03 ? 1 : 0;

        const int tgt = dr3;
        const int dr0_1 = __shfl(dr0, l1i), fu1 = __shfl(fullI, l1i);
        const int dr0_2 = __shfl(dr0, l2i), fu2 = __shfl(fullI, l2i);
        const int dr0_3 = __shfl(dr0, l3i);
        const bool take1 = (kg <= 2) && (dr0_1 == tgt);
        const bool take2 = take1 && fu1 && (kg <= 1) && (dr0_2 == tgt);
        const bool take3 = take2 && fu2 && (kg == 0) && (dr0_3 == tgt);

        const bool h0 = (dr0 != prevv) && (dr0 >= 0);
        const bool h1f = (!e01) && (dr1 >= 0);
        const bool h2f = (!e12) && (dr2 >= 0);
        const bool h3f = (!e23) && (dr3 >= 0);

        float t0v[4], t1v[4], t2v[4], t3v[4];
#pragma unroll
        for (int nb2 = 0; nb2 < 4; nb2++) {
            const float bias = bias3[nb2];
            const float v0 = silu_f(acc2p[nb2][0] + bias);
            const float v1 = silu_f(acc2p[nb2][1] + bias);
            const float v2 = silu_f(acc2p[nb2][2] + bias);
            const float v3 = silu_f(acc2p[nb2][3] + bias);
            float lead = v0 + (c01 ? v1 : 0.f) + (c02 ? v2 : 0.f) + (c03 ? v3 : 0.f);
            float ext = 0.f;
            const float le1 = __shfl(lead, l1i);
            const float le2 = __shfl(lead, l2i);
            const float le3 = __shfl(lead, l3i);
            if (take1) ext += le1;
            if (take2) ext += le2;
            if (take3) ext += le3;
            t0v[nb2] = lead + (c03 ? ext : 0.f);
            t1v[nb2] = v1 + (c12 ? v2 : 0.f) + (c13 ? (v3 + ext) : 0.f);
            t2v[nb2] = v2 + (e23 ? (v3 + ext) : 0.f);
            t3v[nb2] = v3 + ext;
        }
        if (h0) {
            float* p = xout + (size_t)dr0 * 64 + lm;
#pragma unroll
            for (int nb2 = 0; nb2 < 4; nb2++) atomicAdd(p + nb2 * 16, t0v[nb2]);
        }
        if (h1f) {
            float* p = xout + (size_t)dr1 * 64 + lm;
#pragma unroll
            for (int nb2 = 0; nb2 < 4; nb2++) atomicAdd(p + nb2 * 16, t1v[nb2]);
        }
        if (h2f) {
            float* p = xout + (size_t)dr2 * 64 + lm;
#pragma unroll
            for (int nb2 = 0; nb2 < 4; nb2++) atomicAdd(p + nb2 * 16, t2v[nb2]);
        }
        if (h3f) {
            float* p = xout + (size_t)dr3 * 64 + lm;
#pragma unroll
            for (int nb2 = 0; nb2 < 4; nb2++) atomicAdd(p + nb2 * 16, t3v[nb2]);
        }
    }
    asm volatile("s_waitcnt vmcnt(0)" ::: "memory");
}

// ---------------------------------------------------------------------------
// Fused pooling + readout head: one block per graph.
// ---------------------------------------------------------------------------
__global__ void pool_head_kernel(const float* __restrict__ xf, const float* __restrict__ u,
                                 const float* __restrict__ LW1, const float* __restrict__ Lb1,
                                 const float* __restrict__ LW2, const float* __restrict__ Lb2,
                                 const float* __restrict__ LW3, const float* __restrict__ Lb3,
                                 float* __restrict__ out, int N, int G) {
    int g = blockIdx.x;
    int t = threadIdx.x;
    int ch = t & 63, sub = t >> 6;
    long long n0 = ((long long)g * N + G - 1) / G;
    long long n1 = ((long long)(g + 1) * N + G - 1) / G;
    float sm = 0.f, mx = -3.0e38f;
    for (long long n = n0 + sub; n < n1; n += 4) {
        float v = xf[n * 64 + ch];
        sm += v;
        mx = fmaxf(mx, v);
    }
    __shared__ float ssum[256], smax[256];
    __shared__ float pl[194];
    __shared__ float hl[64];
    ssum[t] = sm;
    smax[t] = mx;
    __syncthreads();
    if (sub == 0) {
        float a = ssum[ch] + ssum[64 + ch] + ssum[128 + ch] + ssum[192 + ch];
        float m = fmaxf(fmaxf(smax[ch], smax[64 + ch]), fmaxf(smax[128 + ch], smax[192 + ch]));
        float cnt = (float)(n1 - n0);
        pl[ch] = a;
        pl[64 + ch] = a / fmaxf(cnt, 1.f);
        pl[128 + ch] = m;
    }
    if (t == 0) {
        pl[192] = u[g * 2];
        pl[193] = u[g * 2 + 1];
    }
    __syncthreads();
    float a = 0.f;
    if (t < 64) {
        a = Lb1[t];
        for (int k = 0; k < 194; k++) a += pl[k] * LW1[k * 64 + t];
        a = a / (1.0f + __expf(-a));
        hl[t] = a;
    }
    __syncthreads();
    float b = 0.f;
    if (t < 64) {
        b = Lb2[t];
        for (int k = 0; k < 64; k++) b += hl[k] * LW2[k * 64 + t];
        b = b / (1.0f + __expf(-b));
    }
    __syncthreads();
    if (t < 64) hl[t] = b;
    __syncthreads();
    if (t < 2) {
        float c = Lb3[t];
        for (int k = 0; k < 64; k++) c += hl[k] * LW3[k * 2 + t];
        out[g * 2 + t] = c;
    }
}

// ---------------------------------------------------------------------------
extern "C" void kernel_launch(void* const* d_in, const int* in_sizes, int n_in,
                              void* d_out, int out_size, void* d_ws, size_t ws_size,
                              hipStream_t stream) {
    const float* x   = (const float*)d_in[0];
    const float* u   = (const float*)d_in[1];
    const int*   ei  = (const int*)d_in[2];
    const float* W1  = (const float*)d_in[4];
    const float* b1  = (const float*)d_in[5];
    const float* W2  = (const float*)d_in[6];
    const float* b2  = (const float*)d_in[7];
    const float* W3  = (const float*)d_in[8];
    const float* b3  = (const float*)d_in[9];
    const float* LW1 = (const float*)d_in[10];
    const float* Lb1 = (const float*)d_in[11];
    const float* LW2 = (const float*)d_in[12];
    const float* Lb2 = (const float*)d_in[13];
    const float* LW3 = (const float*)d_in[14];
    const float* Lb3 = (const float*)d_in[15];

    const int N = in_sizes[0] / 64;
    const int G = in_sizes[1] / 2;
    const int E = in_sizes[2] / 2;
    const int L = in_sizes[4] / (126 * 128);

    char* ws = (char*)d_ws;
    size_t off = 0;
    auto alloc = [&](size_t bytes) -> char* {
        char* p = ws + off;
        off += (bytes + 511) & ~(size_t)511;
        return p;
    };
    f16*    PQ     = (f16*)alloc((size_t)N * 256 * 2);
    float4* C      = (float4*)alloc((size_t)N * 16);
    float*  x1     = (float*)alloc((size_t)N * 64 * 4);
    float*  x2     = (float*)alloc((size_t)N * 64 * 4);
    int2*   sd     = (int2*)alloc((size_t)E * 8);
    int*    deg    = (int*)alloc((size_t)N * 4);
    int*    rowst  = (int*)alloc((size_t)N * 4);
    int*    cursor = (int*)alloc((size_t)N * 4);
    int*    bsum   = (int*)alloc(4096);
    int*    boff   = (int*)alloc(4096);
    f16*    B1T    = (f16*)alloc((size_t)L * 256 * 64 * 2);
    f16*    W2T    = (f16*)alloc((size_t)L * 128 * 128 * 2);
    f16*    W3T    = (f16*)alloc((size_t)L * 64 * 128 * 2);
    f16*    w1c    = (f16*)alloc((size_t)L * 128 * 2);
    (void)ws_size;
    (void)n_in;
    (void)out_size;

    hipMemsetAsync(deg, 0, (size_t)N * 4, stream);
    hipMemsetAsync(cursor, 0, (size_t)N * 4, stream);
    hipMemsetAsync(x1, 0, (size_t)N * 64 * 4, stream);
    hipMemsetAsync(x2, 0, (size_t)N * 64 * 4, stream);

    {
        int total = L * (16384 + 16384 + 8192 + 128);
        prep_kernel<<<(total + 255) / 256, 256, 0, stream>>>(W1, W2, W3, B1T, W2T, W3T, w1c, L, total);
    }
    hist_kernel<<<(E + 255) / 256, 256, 0, stream>>>(ei, deg, E);
    int NB = (N + 255) / 256;
    scan_part<<<NB, 256, 0, stream>>>(deg, bsum, N);
    scan_mid<<<1, 512, 0, stream>>>(bsum, boff, NB);
    scan_final<<<NB, 256, 0, stream>>>(deg, boff, rowst, N);
    scatter_kernel<<<(E + 255) / 256, 256, 0, stream>>>(ei, rowst, cursor, sd, E);

    const float* xcur = x;
    const int wtiles = (E + 15) / 16;
    const int ntiles_node = (N + 63) / 64;
    for (int l = 0; l < L; l++) {
        node_kernel<<<768, 256, 0, stream>>>(xcur, B1T + (size_t)l * 16384, b1 + l * 128,
                                             PQ, C, N, ntiles_node);
        float* xo = (l & 1) ? x2 : x1;
        edge_kernel<<<512, 256, 0, stream>>>(PQ, C, sd,
                                             W2T + (size_t)l * 16384, W3T + (size_t)l * 8192,
                                             w1c + l * 128, b2 + l * 128, b3 + l * 64,
                                             xo, E, wtiles);
        xcur = xo;
    }
    pool_head_kernel<<<G, 256, 0, stream>>>(xcur, u, LW1, Lb1, LW2, Lb2, LW3, Lb3,
                                            (float*)d_out, N, G);
}

// Round 9
// 951.439 us; speedup vs baseline: 1.1909x; 1.1909x over previous
//
#include <hip/hip_runtime.h>
#include <hip/hip_bf16.h>

typedef _Float16 f16;
typedef _Float16 f16x8 __attribute__((ext_vector_type(8)));
typedef float    f32x4 __attribute__((ext_vector_type(4)));
typedef float    f32x8 __attribute__((ext_vector_type(8)));

__device__ __forceinline__ float silu_f(float x) {
    return x * __builtin_amdgcn_rcpf(1.0f + __expf(-x));
}

// f16 transcendentals via asm (types routed through short for constraint safety)
__device__ __forceinline__ f16 exp2h(f16 x) {
    short r, xs = __builtin_bit_cast(short, x);
    asm("v_exp_f16 %0, %1" : "=v"(r) : "v"(xs));
    return __builtin_bit_cast(f16, r);
}
__device__ __forceinline__ f16 rcph(f16 x) {
    short r, xs = __builtin_bit_cast(short, x);
    asm("v_rcp_f16 %0, %1" : "=v"(r) : "v"(xs));
    return __builtin_bit_cast(f16, r);
}
// packed-f16 silu: x * rcp(1 + exp2(-log2e * x)); tails exact via inf/0
__device__ __forceinline__ f16x8 silu_h8(f16x8 x) {
    f16x8 t = x * (f16)(-1.442695040f);
    f16x8 e;
#pragma unroll
    for (int j = 0; j < 8; j++) e[j] = exp2h(t[j]);
    f16x8 d = e + (f16)1.0f;
    f16x8 r;
#pragma unroll
    for (int j = 0; j < 8; j++) r[j] = rcph(d[j]);
    return x * r;
}

// async 16B/lane global->LDS DMA
__device__ __forceinline__ void load_lds16(const f16* g, f16* l) {
    __builtin_amdgcn_global_load_lds(
        (const __attribute__((address_space(1))) void*)g,
        (__attribute__((address_space(3))) void*)l, 16, 0, 0);
}

// ---------------------------------------------------------------------------
// Weight prep: B1T[l][256][64], W2T[l][128][128], W3T[l][64][128], w1c f16
// ---------------------------------------------------------------------------
__global__ void prep_kernel(const float* __restrict__ W1, const float* __restrict__ W2,
                            const float* __restrict__ W3, f16* __restrict__ B1T,
                            f16* __restrict__ W2T, f16* __restrict__ W3T,
                            f16* __restrict__ w1c, int L, int total) {
    int idx = blockIdx.x * 256 + threadIdx.x;
    if (idx >= total) return;
    const int per = 16384 + 16384 + 8192 + 128;
    int l = idx / per, r = idx % per;
    const float* W1l = W1 + (size_t)l * 126 * 128;
    if (r < 16384) {
        int c = r >> 6, k = r & 63;
        float v;
        if (c < 128) v = W1l[k * 128 + c];
        else v = (k >= 3) ? W1l[(64 + k - 3) * 128 + (c - 128)] : 0.0f;
        B1T[(size_t)l * 16384 + r] = (f16)v;
    } else if (r < 32768) {
        int q = r - 16384, n = q >> 7, k = q & 127;
        W2T[(size_t)l * 16384 + q] = (f16)W2[(size_t)l * 16384 + k * 128 + n];
    } else if (r < 40960) {
        int q = r - 32768, n = q >> 7, k = q & 127;
        W3T[(size_t)l * 8192 + q] = (f16)W3[(size_t)l * 8192 + k * 64 + n];
    } else {
        int c = r - 40960;
        w1c[l * 128 + c] = (f16)W1l[125 * 128 + c];
    }
}

// ---------------------------------------------------------------------------
// CSR build: histogram, 2-level scan, counting-sort scatter (int2 payload)
// ---------------------------------------------------------------------------
__global__ void hist_kernel(const int* __restrict__ ei, int* __restrict__ deg, int E) {
    int i = blockIdx.x * 256 + threadIdx.x;
    if (i < E) atomicAdd(&deg[ei[E + i]], 1);
}

__global__ void scan_part(const int* __restrict__ deg, int* __restrict__ bsum, int N) {
    __shared__ int red[256];
    int t = threadIdx.x;
    int i = blockIdx.x * 256 + t;
    red[t] = (i < N) ? deg[i] : 0;
    __syncthreads();
    for (int s = 128; s > 0; s >>= 1) {
        if (t < s) red[t] += red[t + s];
        __syncthreads();
    }
    if (t == 0) bsum[blockIdx.x] = red[0];
}

__global__ void scan_mid(const int* __restrict__ bsum, int* __restrict__ boff, int nb) {
    __shared__ int sm[512];
    int t = threadIdx.x;
    int v = (t < nb) ? bsum[t] : 0;
    sm[t] = v;
    __syncthreads();
    for (int off = 1; off < 512; off <<= 1) {
        int a = (t >= off) ? sm[t - off] : 0;
        __syncthreads();
        sm[t] += a;
        __syncthreads();
    }
    if (t < nb) boff[t] = sm[t] - v;
}

__global__ void scan_final(const int* __restrict__ deg, const int* __restrict__ boff,
                           int* __restrict__ row_start, int N) {
    __shared__ int sm[256];
    int t = threadIdx.x;
    int i = blockIdx.x * 256 + t;
    int v = (i < N) ? deg[i] : 0;
    sm[t] = v;
    __syncthreads();
    for (int off = 1; off < 256; off <<= 1) {
        int a = (t >= off) ? sm[t - off] : 0;
        __syncthreads();
        sm[t] += a;
        __syncthreads();
    }
    if (i < N) row_start[i] = boff[blockIdx.x] + sm[t] - v;
}

__global__ void scatter_kernel(const int* __restrict__ ei, const int* __restrict__ row_start,
                               int* __restrict__ cursor, int2* __restrict__ sd, int E) {
    int i = blockIdx.x * 256 + threadIdx.x;
    if (i < E) {
        int d = ei[E + i];
        int p = row_start[d] + atomicAdd(&cursor[d], 1);
        sd[p] = make_int2(ei[i], d);
    }
}

// ---------------------------------------------------------------------------
// Node kernel: PQ[n][0:128] = x@W1a + b1 ; PQ[n][128:256] = x[3:]@W1b ; C=xyz
// ---------------------------------------------------------------------------
__global__ __launch_bounds__(256, 3) void node_kernel(
    const float* __restrict__ x, const f16* __restrict__ B1T,
    const float* __restrict__ b1, f16* __restrict__ PQ,
    float4* __restrict__ C, int N, int ntiles) {
    __shared__ f16 b1t[256 * 72];
    const int tid = threadIdx.x;
    const int w = tid >> 6, lane = tid & 63, lm = lane & 15, kg = lane >> 4;

    for (int i = tid; i < 256 * 64; i += 256)
        b1t[(i >> 6) * 72 + (i & 63)] = B1T[i];
    __syncthreads();

    for (int tile = blockIdx.x; tile < ntiles; tile += gridDim.x) {
        const int base = tile * 64;
        int ar = base + w * 16 + lm;
        if (ar >= N) ar = N - 1;

        f16x8 afrag[2];
#pragma unroll
        for (int ks = 0; ks < 2; ks++) {
            f32x8 v = *(const f32x8*)(x + (size_t)ar * 64 + ks * 32 + kg * 8);
            f16x8 h;
#pragma unroll
            for (int j = 0; j < 8; j++) h[j] = (f16)v[j];
            afrag[ks] = h;
        }

        f32x4 acc[16];
#pragma unroll
        for (int nb = 0; nb < 16; nb++) acc[nb] = (f32x4){0.f, 0.f, 0.f, 0.f};
#pragma unroll
        for (int ks = 0; ks < 2; ks++)
#pragma unroll
            for (int nb = 0; nb < 16; nb++) {
                f16x8 b = *(const f16x8*)&b1t[(nb * 16 + lm) * 72 + ks * 32 + kg * 8];
                acc[nb] = __builtin_amdgcn_mfma_f32_16x16x32_f16(afrag[ks], b, acc[nb], 0, 0, 0);
            }

#pragma unroll
        for (int nb = 0; nb < 16; nb++) {
            int col = nb * 16 + lm;
            float bias = (col < 128) ? b1[col] : 0.0f;
#pragma unroll
            for (int reg = 0; reg < 4; reg++) {
                int orow = base + w * 16 + kg * 4 + reg;
                if (orow < N) PQ[(size_t)orow * 256 + col] = (f16)(acc[nb][reg] + bias);
            }
        }
        if (tid < 64) {
            int n = base + tid;
            if (n < N) {
                const float* xr = x + (size_t)n * 64;
                C[n] = make_float4(xr[0], xr[1], xr[2], 0.0f);
            }
        }
    }
}

// ---------------------------------------------------------------------------
// Edge kernel v9 = R5 structure (the 320us best) + packed-f16 h1 silu + int2 sd.
//   p|q both DMA-staged (32KB); W2T in LDS (32KB XOR-swizzled); W3T global/L1;
//   deferred-epilogue atomics; wait vmcnt(3) (pending sd(1)+C(2)).
// LDS 32+32+4.5 = 68.5KB -> 2 blocks/CU (the R7 w3t-in-LDS at 84.5KB was a
// 1-block/CU occupancy regression: 320->379us).
// ---------------------------------------------------------------------------
__global__ __launch_bounds__(256, 2) void edge_kernel(
    const f16* __restrict__ PQ, const float4* __restrict__ C,
    const int2* __restrict__ sd,
    const f16* __restrict__ W2T, const f16* __restrict__ W3T,
    const f16* __restrict__ w1c, const float* __restrict__ b2,
    const float* __restrict__ b3, float* __restrict__ xout,
    int E, int wtiles) {
    __shared__ f16 w2t[128 * 128];       // 32KB XOR-swizzled
    __shared__ f16 stage[4 * 4096];      // 32KB per-wave p|q
    __shared__ f16 tb[4 * 576];          // 4.5KB per-wave transpose slices

    const int tid = threadIdx.x;
    const int w = tid >> 6, lane = tid & 63, lm = lane & 15, kg = lane >> 4;
    const int e4 = lane >> 2, c4 = lane & 3;

    for (int i = tid; i < 128 * 128; i += 256) {
        int n = i >> 7, k = i & 127;
        w2t[n * 128 + (((k >> 3) ^ (n & 15)) << 3) + (k & 7)] = W2T[i];
    }

    // loop-invariant hoists
    f16x8 wvh[4];
#pragma unroll
    for (int ks = 0; ks < 4; ks++) wvh[ks] = *(const f16x8*)(w1c + ks * 32 + kg * 8);
    float bias2[8], bias3[4];
#pragma unroll
    for (int nb = 0; nb < 8; nb++) bias2[nb] = b2[nb * 16 + lm];
#pragma unroll
    for (int nb = 0; nb < 4; nb++) bias3[nb] = b3[nb * 16 + lm];
    __syncthreads();   // w2t ready; no barriers after this

    f16* sw = stage + w * 4096;          // p at 0, q at 2048
    f16* tq = tb + w * 576;
    const int nwaves = gridDim.x * 4;
    const int r0 = kg * 4;
    const int l1i = (lane + 16) & 63, l2i = (lane + 32) & 63, l3i = (lane + 48) & 63;

    // ---- prologue ----
    int t = blockIdx.x * 4 + w;
    if (t >= wtiles) return;
    int e0 = t * 16 + lm;
    int erc = min(e0, E - 1);
    int2 sd0 = sd[erc];
    int scl = sd0.x, dcl = sd0.y;
    int dsen_cur = (e0 < E) ? dcl : -1;
    {   // DMA(t)
        int de = __shfl(dcl, e4), se = __shfl(scl, e4);
        const f16* gp = PQ + (size_t)de * 256 + c4 * 8;
        const f16* gq = PQ + (size_t)se * 256 + 128 + c4 * 8;
#pragma unroll
        for (int j = 0; j < 4; j++) load_lds16(gp + j * 32, sw + j * 512 + lane * 8);
#pragma unroll
        for (int j = 0; j < 4; j++) load_lds16(gq + j * 32, sw + 2048 + j * 512 + lane * 8);
    }
    int e1 = (t + nwaves) * 16 + lm;
    int erc1 = min(max(e1, 0), E - 1);
    int2 sdn = sd[erc1];
    int s_nx = sdn.x, d_nx = sdn.y;
    int e_nx_ok = (e1 < E) ? 1 : 0;
    float4 cs = C[scl], cd = C[dcl];

    f32x4 acc2p[4];
#pragma unroll
    for (int nb2 = 0; nb2 < 4; nb2++) acc2p[nb2] = (f32x4){0.f, 0.f, 0.f, 0.f};
    int dsen_prev = -1;

    while (true) {
        const int tn = t + nwaves;

        // ---- 1. stage(t) ready: drain atomics+DMA, leave sd+C (3) ----
        asm volatile("s_waitcnt vmcnt(3)" ::: "memory");

        float dx = cs.x - cd.x, dy = cs.y - cd.y, dz = cs.z - cd.z;
        float dist2 = dx * dx + dy * dy + dz * dz;
        f16 d2h = (f16)dist2;

        // ---- 2. h1: packed f16 (pk_add/pk_fma + f16 silu) ----
        f16x8 afrag[4];
#pragma unroll
        for (int ks = 0; ks < 4; ks++) {
            f16x8 p = *(const f16x8*)&sw[ks * 512 + lm * 32 + kg * 8];
            f16x8 q = *(const f16x8*)&sw[2048 + ks * 512 + lm * 32 + kg * 8];
            f16x8 xv = p + q + d2h * wvh[ks];
            afrag[ks] = silu_h8(xv);
        }

        // ---- GEMM1: h1 @ W2 ----
        f32x4 acc1[8];
#pragma unroll
        for (int nb = 0; nb < 8; nb++) acc1[nb] = (f32x4){0.f, 0.f, 0.f, 0.f};
#pragma unroll
        for (int ks = 0; ks < 4; ks++)
#pragma unroll
            for (int nb = 0; nb < 8; nb++) {
                int n = nb * 16 + lm;
                f16x8 b = *(const f16x8*)&w2t[n * 128 + (((ks * 4 + kg) ^ (n & 15)) << 3)];
                acc1[nb] = __builtin_amdgcn_mfma_f32_16x16x32_f16(afrag[ks], b, acc1[nb], 0, 0, 0);
            }

        // ---- 3. deferred epilogue for PREVIOUS tile (atomics precede DMA) ----
        {
            const int dr0 = __shfl(dsen_prev, r0);
            const int dr1 = __shfl(dsen_prev, r0 + 1);
            const int dr2 = __shfl(dsen_prev, r0 + 2);
            const int dr3 = __shfl(dsen_prev, r0 + 3);
            int prevv = __shfl(dsen_prev, (r0 - 1) & 63);
            if (kg == 0) prevv = -1234567;

            const bool e01 = dr0 == dr1, e12 = dr1 == dr2, e23 = dr2 == dr3;
            const bool c01 = e01, c02 = e01 && e12, c03 = c02 && e23;
            const bool c12 = e12, c13 = e12 && e23;
            const int fullI = c03 ? 1 : 0;

            const int tgt = dr3;
            const int dr0_1 = __shfl(dr0, l1i), fu1 = __shfl(fullI, l1i);
            const int dr0_2 = __shfl(dr0, l2i), fu2 = __shfl(fullI, l2i);
            const int dr0_3 = __shfl(dr0, l3i);
            const bool take1 = (kg <= 2) && (dr0_1 == tgt);
            const bool take2 = take1 && fu1 && (kg <= 1) && (dr0_2 == tgt);
            const bool take3 = take2 && fu2 && (kg == 0) && (dr0_3 == tgt);

            const bool h0 = (dr0 != prevv) && (dr0 >= 0);
            const bool h1f = (!e01) && (dr1 >= 0);
            const bool h2f = (!e12) && (dr2 >= 0);
            const bool h3f = (!e23) && (dr3 >= 0);

            float t0v[4], t1v[4], t2v[4], t3v[4];
#pragma unroll
            for (int nb2 = 0; nb2 < 4; nb2++) {
                const float bias = bias3[nb2];
                const float v0 = silu_f(acc2p[nb2][0] + bias);
                const float v1 = silu_f(acc2p[nb2][1] + bias);
                const float v2 = silu_f(acc2p[nb2][2] + bias);
                const float v3 = silu_f(acc2p[nb2][3] + bias);
                float lead = v0 + (c01 ? v1 : 0.f) + (c02 ? v2 : 0.f) + (c03 ? v3 : 0.f);
                float ext = 0.f;
                const float le1 = __shfl(lead, l1i);
                const float le2 = __shfl(lead, l2i);
                const float le3 = __shfl(lead, l3i);
                if (take1) ext += le1;
                if (take2) ext += le2;
                if (take3) ext += le3;
                t0v[nb2] = lead + (c03 ? ext : 0.f);
                t1v[nb2] = v1 + (c12 ? v2 : 0.f) + (c13 ? (v3 + ext) : 0.f);
                t2v[nb2] = v2 + (e23 ? (v3 + ext) : 0.f);
                t3v[nb2] = v3 + ext;
            }
            if (h0) {
                float* p = xout + (size_t)dr0 * 64 + lm;
#pragma unroll
                for (int nb2 = 0; nb2 < 4; nb2++) atomicAdd(p + nb2 * 16, t0v[nb2]);
            }
            if (h1f) {
                float* p = xout + (size_t)dr1 * 64 + lm;
#pragma unroll
                for (int nb2 = 0; nb2 < 4; nb2++) atomicAdd(p + nb2 * 16, t1v[nb2]);
            }
            if (h2f) {
                float* p = xout + (size_t)dr2 * 64 + lm;
#pragma unroll
                for (int nb2 = 0; nb2 < 4; nb2++) atomicAdd(p + nb2 * 16, t2v[nb2]);
            }
            if (h3f) {
                float* p = xout + (size_t)dr3 * 64 + lm;
#pragma unroll
                for (int nb2 = 0; nb2 < 4; nb2++) atomicAdd(p + nb2 * 16, t3v[nb2]);
            }
        }

        // ---- 4. DMA(t+nw) into stage ----
        int dsen_nx = e_nx_ok ? d_nx : -1;
        if (tn < wtiles) {
            int de = __shfl(d_nx, e4), se = __shfl(s_nx, e4);
            const f16* gp = PQ + (size_t)de * 256 + c4 * 8;
            const f16* gq = PQ + (size_t)se * 256 + 128 + c4 * 8;
#pragma unroll
            for (int j = 0; j < 4; j++) load_lds16(gp + j * 32, sw + j * 512 + lane * 8);
#pragma unroll
            for (int j = 0; j < 4; j++) load_lds16(gq + j * 32, sw + 2048 + j * 512 + lane * 8);
        }

        // ---- 5. sd(t+2nw) and C(t+nw): the 3 left pending ----
        int e2 = (tn + nwaves) * 16 + lm;
        int erc2 = min(max(e2, 0), E - 1);
        int2 sd2 = sd[erc2];
        int e_nx2_ok = (e2 < E) ? 1 : 0;
        float4 cs2 = C[s_nx], cd2 = C[d_nx];

        // ---- 6. GEMM2 in 4 k-quarters (W3T via global/L1) ----
        f32x4 acc2[4];
#pragma unroll
        for (int nb2 = 0; nb2 < 4; nb2++) acc2[nb2] = (f32x4){0.f, 0.f, 0.f, 0.f};
#pragma unroll
        for (int kq = 0; kq < 4; kq++) {
#pragma unroll
            for (int nn = 0; nn < 2; nn++) {
                int nb = kq * 2 + nn;
#pragma unroll
                for (int reg = 0; reg < 4; reg++)
                    tq[(kg * 4 + reg) * 36 + nn * 16 + lm] =
                        (f16)silu_f(acc1[nb][reg] + bias2[nb]);
            }
            f16x8 a2 = *(const f16x8*)&tq[lm * 36 + kg * 8];
#pragma unroll
            for (int nb2 = 0; nb2 < 4; nb2++) {
                f16x8 b = *(const f16x8*)(W3T + (size_t)(nb2 * 16 + lm) * 128 +
                                          kq * 32 + kg * 8);
                acc2[nb2] = __builtin_amdgcn_mfma_f32_16x16x32_f16(a2, b, acc2[nb2], 0, 0, 0);
            }
        }

        // ---- 7. rotate pipeline state ----
#pragma unroll
        for (int nb2 = 0; nb2 < 4; nb2++) acc2p[nb2] = acc2[nb2];
        dsen_prev = dsen_cur;
        dsen_cur = dsen_nx;
        s_nx = sd2.x; d_nx = sd2.y; e_nx_ok = e_nx2_ok;
        cs = cs2; cd = cd2;
        t = tn;
        if (t >= wtiles) break;
    }

    // ---- final deferred epilogue ----
    {
        const int dr0 = __shfl(dsen_prev, r0);
        const int dr1 = __shfl(dsen_prev, r0 + 1);
        const int dr2 = __shfl(dsen_prev, r0 + 2);
        const int dr3 = __shfl(dsen_prev, r0 + 3);
        int prevv = __shfl(dsen_prev, (r0 - 1) & 63);
        if (kg == 0) prevv = -1234567;

        const bool e01 = dr0 == dr1, e12 = dr1 == dr2, e23 = dr2 == dr3;
        const bool c01 = e01, c02 = e01 && e12, c03 = c02 && e23;
        const bool c12 = e12, c13 = e12 && e23;
        const int fullI = c03 ? 1 : 0;

        const int tgt = dr3;
        const int dr0_1 = __shfl(dr0, l1i), fu1 = __shfl(fullI, l1i);
        const int dr0_2 = __shfl(dr0, l2i), fu2 = __shfl(fullI, l2i);
        const int dr0_3 = __shfl(dr0, l3i);
        const bool take1 = (kg <= 2) && (dr0_1 == tgt);
        const bool take2 = take1 && fu1 && (kg <= 1) && (dr0_2 == tgt);
        const bool take3 = take2 && fu2 && (kg == 0) && (dr0_3 == tgt);

        const bool h0 = (dr0 != prevv) && (dr0 >= 0);
        const bool h1f = (!e01) && (dr1 >= 0);
        const bool h2f = (!e12) && (dr2 >= 0);
        const bool h3f = (!e23) && (dr3 >= 0);

        float t0v[4], t1v[4], t2v[4], t3v[4];
#pragma unroll
        for (int nb2 = 0; nb2 < 4; nb2++) {
            const float bias = bias3[nb2];
            const float v0 = silu_f(acc2p[nb2][0] + bias);
            const float v1 = silu_f(acc2p[nb2][1] + bias);
            const float v2 = silu_f(acc2p[nb2][2] + bias);
            const float v3 = silu_f(acc2p[nb2][3] + bias);
            float lead = v0 + (c01 ? v1 : 0.f) + (c02 ? v2 : 0.f) + (c03 ? v3 : 0.f);
            float ext = 0.f;
            const float le1 = __shfl(lead, l1i);
            const float le2 = __shfl(lead, l2i);
            const float le3 = __shfl(lead, l3i);
            if (take1) ext += le1;
            if (take2) ext += le2;
            if (take3) ext += le3;
            t0v[nb2] = lead + (c03 ? ext : 0.f);
            t1v[nb2] = v1 + (c12 ? v2 : 0.f) + (c13 ? (v3 + ext) : 0.f);
            t2v[nb2] = v2 + (e23 ? (v3 + ext) : 0.f);
            t3v[nb2] = v3 + ext;
        }
        if (h0) {
            float* p = xout + (size_t)dr0 * 64 + lm;
#pragma unroll
            for (int nb2 = 0; nb2 < 4; nb2++) atomicAdd(p + nb2 * 16, t0v[nb2]);
        }
        if (h1f) {
            float* p = xout + (size_t)dr1 * 64 + lm;
#pragma unroll
            for (int nb2 = 0; nb2 < 4; nb2++) atomicAdd(p + nb2 * 16, t1v[nb2]);
        }
        if (h2f) {
            float* p = xout + (size_t)dr2 * 64 + lm;
#pragma unroll
            for (int nb2 = 0; nb2 < 4; nb2++) atomicAdd(p + nb2 * 16, t2v[nb2]);
        }
        if (h3f) {
            float* p = xout + (size_t)dr3 * 64 + lm;
#pragma unroll
            for (int nb2 = 0; nb2 < 4; nb2++) atomicAdd(p + nb2 * 16, t3v[nb2]);
        }
    }
    asm volatile("s_waitcnt vmcnt(0)" ::: "memory");
}

// ---------------------------------------------------------------------------
// Fused pooling + readout head: one block per graph.
// ---------------------------------------------------------------------------
__global__ void pool_head_kernel(const float* __restrict__ xf, const float* __restrict__ u,
                                 const float* __restrict__ LW1, const float* __restrict__ Lb1,
                                 const float* __restrict__ LW2, const float* __restrict__ Lb2,
                                 const float* __restrict__ LW3, const float* __restrict__ Lb3,
                                 float* __restrict__ out, int N, int G) {
    int g = blockIdx.x;
    int t = threadIdx.x;
    int ch = t & 63, sub = t >> 6;
    long long n0 = ((long long)g * N + G - 1) / G;
    long long n1 = ((long long)(g + 1) * N + G - 1) / G;
    float sm = 0.f, mx = -3.0e38f;
    for (long long n = n0 + sub; n < n1; n += 4) {
        float v = xf[n * 64 + ch];
        sm += v;
        mx = fmaxf(mx, v);
    }
    __shared__ float ssum[256], smax[256];
    __shared__ float pl[194];
    __shared__ float hl[64];
    ssum[t] = sm;
    smax[t] = mx;
    __syncthreads();
    if (sub == 0) {
        float a = ssum[ch] + ssum[64 + ch] + ssum[128 + ch] + ssum[192 + ch];
        float m = fmaxf(fmaxf(smax[ch], smax[64 + ch]), fmaxf(smax[128 + ch], smax[192 + ch]));
        float cnt = (float)(n1 - n0);
        pl[ch] = a;
        pl[64 + ch] = a / fmaxf(cnt, 1.f);
        pl[128 + ch] = m;
    }
    if (t == 0) {
        pl[192] = u[g * 2];
        pl[193] = u[g * 2 + 1];
    }
    __syncthreads();
    float a = 0.f;
    if (t < 64) {
        a = Lb1[t];
        for (int k = 0; k < 194; k++) a += pl[k] * LW1[k * 64 + t];
        a = a / (1.0f + __expf(-a));
        hl[t] = a;
    }
    __syncthreads();
    float b = 0.f;
    if (t < 64) {
        b = Lb2[t];
        for (int k = 0; k < 64; k++) b += hl[k] * LW2[k * 64 + t];
        b = b / (1.0f + __expf(-b));
    }
    __syncthreads();
    if (t < 64) hl[t] = b;
    __syncthreads();
    if (t < 2) {
        float c = Lb3[t];
        for (int k = 0; k < 64; k++) c += hl[k] * LW3[k * 2 + t];
        out[g * 2 + t] = c;
    }
}

// ---------------------------------------------------------------------------
extern "C" void kernel_launch(void* const* d_in, const int* in_sizes, int n_in,
                              void* d_out, int out_size, void* d_ws, size_t ws_size,
                              hipStream_t stream) {
    const float* x   = (const float*)d_in[0];
    const float* u   = (const float*)d_in[1];
    const int*   ei  = (const int*)d_in[2];
    const float* W1  = (const float*)d_in[4];
    const float* b1  = (const float*)d_in[5];
    const float* W2  = (const float*)d_in[6];
    const float* b2  = (const float*)d_in[7];
    const float* W3  = (const float*)d_in[8];
    const float* b3  = (const float*)d_in[9];
    const float* LW1 = (const float*)d_in[10];
    const float* Lb1 = (const float*)d_in[11];
    const float* LW2 = (const float*)d_in[12];
    const float* Lb2 = (const float*)d_in[13];
    const float* LW3 = (const float*)d_in[14];
    const float* Lb3 = (const float*)d_in[15];

    const int N = in_sizes[0] / 64;
    const int G = in_sizes[1] / 2;
    const int E = in_sizes[2] / 2;
    const int L = in_sizes[4] / (126 * 128);

    char* ws = (char*)d_ws;
    size_t off = 0;
    auto alloc = [&](size_t bytes) -> char* {
        char* p = ws + off;
        off += (bytes + 511) & ~(size_t)511;
        return p;
    };
    f16*    PQ     = (f16*)alloc((size_t)N * 256 * 2);
    float4* C      = (float4*)alloc((size_t)N * 16);
    float*  x1     = (float*)alloc((size_t)N * 64 * 4);
    float*  x2     = (float*)alloc((size_t)N * 64 * 4);
    int2*   sd     = (int2*)alloc((size_t)E * 8);
    int*    deg    = (int*)alloc((size_t)N * 4);
    int*    rowst  = (int*)alloc((size_t)N * 4);
    int*    cursor = (int*)alloc((size_t)N * 4);
    int*    bsum   = (int*)alloc(4096);
    int*    boff   = (int*)alloc(4096);
    f16*    B1T    = (f16*)alloc((size_t)L * 256 * 64 * 2);
    f16*    W2T    = (f16*)alloc((size_t)L * 128 * 128 * 2);
    f16*    W3T    = (f16*)alloc((size_t)L * 64 * 128 * 2);
    f16*    w1c    = (f16*)alloc((size_t)L * 128 * 2);
    (void)ws_size;
    (void)n_in;
    (void)out_size;

    hipMemsetAsync(deg, 0, (size_t)N * 4, stream);
    hipMemsetAsync(cursor, 0, (size_t)N * 4, stream);
    hipMemsetAsync(x1, 0, (size_t)N * 64 * 4, stream);
    hipMemsetAsync(x2, 0, (size_t)N * 64 * 4, stream);

    {
        int total = L * (16384 + 16384 + 8192 + 128);
        prep_kernel<<<(total + 255) / 256, 256, 0, stream>>>(W1, W2, W3, B1T, W2T, W3T, w1c, L, total);
    }
    hist_kernel<<<(E + 255) / 256, 256, 0, stream>>>(ei, deg, E);
    int NB = (N + 255) / 256;
    scan_part<<<NB, 256, 0, stream>>>(deg, bsum, N);
    scan_mid<<<1, 512, 0, stream>>>(bsum, boff, NB);
    scan_final<<<NB, 256, 0, stream>>>(deg, boff, rowst, N);
    scatter_kernel<<<(E + 255) / 256, 256, 0, stream>>>(ei, rowst, cursor, sd, E);

    const float* xcur = x;
    const int wtiles = (E + 15) / 16;
    const int ntiles_node = (N + 63) / 64;
    for (int l = 0; l < L; l++) {
        node_kernel<<<768, 256, 0, stream>>>(xcur, B1T + (size_t)l * 16384, b1 + l * 128,
                                             PQ, C, N, ntiles_node);
        float* xo = (l & 1) ? x2 : x1;
        edge_kernel<<<512, 256, 0, stream>>>(PQ, C, sd,
                                             W2T + (size_t)l * 16384, W3T + (size_t)l * 8192,
                                             w1c + l * 128, b2 + l * 128, b3 + l * 64,
                                             xo, E, wtiles);
        xcur = xo;
    }
    pool_head_kernel<<<G, 256, 0, stream>>>(xcur, u, LW1, Lb1, LW2, Lb2, LW3, Lb3,
                                            (float*)d_out, N, G);
}

// Round 10
// 914.009 us; speedup vs baseline: 1.2396x; 1.0410x over previous
//
#include <hip/hip_runtime.h>
#include <hip/hip_bf16.h>

typedef _Float16 f16;
typedef _Float16 f16x8 __attribute__((ext_vector_type(8)));
typedef float    f32x4 __attribute__((ext_vector_type(4)));
typedef float    f32x8 __attribute__((ext_vector_type(8)));

__device__ __forceinline__ float silu_f(float x) {
    return x * __builtin_amdgcn_rcpf(1.0f + __expf(-x));
}

// f16 transcendentals via asm (types routed through short for constraint safety)
__device__ __forceinline__ f16 exp2h(f16 x) {
    short r, xs = __builtin_bit_cast(short, x);
    asm("v_exp_f16 %0, %1" : "=v"(r) : "v"(xs));
    return __builtin_bit_cast(f16, r);
}
__device__ __forceinline__ f16 rcph(f16 x) {
    short r, xs = __builtin_bit_cast(short, x);
    asm("v_rcp_f16 %0, %1" : "=v"(r) : "v"(xs));
    return __builtin_bit_cast(f16, r);
}
// packed-f16 silu: x * rcp(1 + exp2(-log2e * x)); tails exact via inf/0
__device__ __forceinline__ f16x8 silu_h8(f16x8 x) {
    f16x8 t = x * (f16)(-1.442695040f);
    f16x8 e;
#pragma unroll
    for (int j = 0; j < 8; j++) e[j] = exp2h(t[j]);
    f16x8 d = e + (f16)1.0f;
    f16x8 r;
#pragma unroll
    for (int j = 0; j < 8; j++) r[j] = rcph(d[j]);
    return x * r;
}

// async 16B/lane global->LDS DMA
__device__ __forceinline__ void load_lds16(const f16* g, f16* l) {
    __builtin_amdgcn_global_load_lds(
        (const __attribute__((address_space(1))) void*)g,
        (__attribute__((address_space(3))) void*)l, 16, 0, 0);
}

// ---------------------------------------------------------------------------
// Weight prep: B1T[l][256][64], W2T[l][128][128], W3T[l][64][128], w1c f16
// ---------------------------------------------------------------------------
__global__ void prep_kernel(const float* __restrict__ W1, const float* __restrict__ W2,
                            const float* __restrict__ W3, f16* __restrict__ B1T,
                            f16* __restrict__ W2T, f16* __restrict__ W3T,
                            f16* __restrict__ w1c, int L, int total) {
    int idx = blockIdx.x * 256 + threadIdx.x;
    if (idx >= total) return;
    const int per = 16384 + 16384 + 8192 + 128;
    int l = idx / per, r = idx % per;
    const float* W1l = W1 + (size_t)l * 126 * 128;
    if (r < 16384) {
        int c = r >> 6, k = r & 63;
        float v;
        if (c < 128) v = W1l[k * 128 + c];
        else v = (k >= 3) ? W1l[(64 + k - 3) * 128 + (c - 128)] : 0.0f;
        B1T[(size_t)l * 16384 + r] = (f16)v;
    } else if (r < 32768) {
        int q = r - 16384, n = q >> 7, k = q & 127;
        W2T[(size_t)l * 16384 + q] = (f16)W2[(size_t)l * 16384 + k * 128 + n];
    } else if (r < 40960) {
        int q = r - 32768, n = q >> 7, k = q & 127;
        W3T[(size_t)l * 8192 + q] = (f16)W3[(size_t)l * 8192 + k * 64 + n];
    } else {
        int c = r - 40960;
        w1c[l * 128 + c] = (f16)W1l[125 * 128 + c];
    }
}

// ---------------------------------------------------------------------------
// CSR build: histogram, 2-level scan, counting-sort scatter (int2 payload)
// ---------------------------------------------------------------------------
__global__ void hist_kernel(const int* __restrict__ ei, int* __restrict__ deg, int E) {
    int i = blockIdx.x * 256 + threadIdx.x;
    if (i < E) atomicAdd(&deg[ei[E + i]], 1);
}

__global__ void scan_part(const int* __restrict__ deg, int* __restrict__ bsum, int N) {
    __shared__ int red[256];
    int t = threadIdx.x;
    int i = blockIdx.x * 256 + t;
    red[t] = (i < N) ? deg[i] : 0;
    __syncthreads();
    for (int s = 128; s > 0; s >>= 1) {
        if (t < s) red[t] += red[t + s];
        __syncthreads();
    }
    if (t == 0) bsum[blockIdx.x] = red[0];
}

__global__ void scan_mid(const int* __restrict__ bsum, int* __restrict__ boff, int nb) {
    __shared__ int sm[512];
    int t = threadIdx.x;
    int v = (t < nb) ? bsum[t] : 0;
    sm[t] = v;
    __syncthreads();
    for (int off = 1; off < 512; off <<= 1) {
        int a = (t >= off) ? sm[t - off] : 0;
        __syncthreads();
        sm[t] += a;
        __syncthreads();
    }
    if (t < nb) boff[t] = sm[t] - v;
}

__global__ void scan_final(const int* __restrict__ deg, const int* __restrict__ boff,
                           int* __restrict__ row_start, int N) {
    __shared__ int sm[256];
    int t = threadIdx.x;
    int i = blockIdx.x * 256 + t;
    int v = (i < N) ? deg[i] : 0;
    sm[t] = v;
    __syncthreads();
    for (int off = 1; off < 256; off <<= 1) {
        int a = (t >= off) ? sm[t - off] : 0;
        __syncthreads();
        sm[t] += a;
        __syncthreads();
    }
    if (i < N) row_start[i] = boff[blockIdx.x] + sm[t] - v;
}

__global__ void scatter_kernel(const int* __restrict__ ei, const int* __restrict__ row_start,
                               int* __restrict__ cursor, int2* __restrict__ sd, int E) {
    int i = blockIdx.x * 256 + threadIdx.x;
    if (i < E) {
        int d = ei[E + i];
        int p = row_start[d] + atomicAdd(&cursor[d], 1);
        sd[p] = make_int2(ei[i], d);
    }
}

// ---------------------------------------------------------------------------
// Node kernel: PQ[n][0:128] = x@W1a + b1 ; PQ[n][128:256] = x[3:]@W1b ; C=xyz
// ---------------------------------------------------------------------------
__global__ __launch_bounds__(256, 3) void node_kernel(
    const float* __restrict__ x, const f16* __restrict__ B1T,
    const float* __restrict__ b1, f16* __restrict__ PQ,
    float4* __restrict__ C, int N, int ntiles) {
    __shared__ f16 b1t[256 * 72];
    const int tid = threadIdx.x;
    const int w = tid >> 6, lane = tid & 63, lm = lane & 15, kg = lane >> 4;

    for (int i = tid; i < 256 * 64; i += 256)
        b1t[(i >> 6) * 72 + (i & 63)] = B1T[i];
    __syncthreads();

    for (int tile = blockIdx.x; tile < ntiles; tile += gridDim.x) {
        const int base = tile * 64;
        int ar = base + w * 16 + lm;
        if (ar >= N) ar = N - 1;

        f16x8 afrag[2];
#pragma unroll
        for (int ks = 0; ks < 2; ks++) {
            f32x8 v = *(const f32x8*)(x + (size_t)ar * 64 + ks * 32 + kg * 8);
            f16x8 h;
#pragma unroll
            for (int j = 0; j < 8; j++) h[j] = (f16)v[j];
            afrag[ks] = h;
        }

        f32x4 acc[16];
#pragma unroll
        for (int nb = 0; nb < 16; nb++) acc[nb] = (f32x4){0.f, 0.f, 0.f, 0.f};
#pragma unroll
        for (int ks = 0; ks < 2; ks++)
#pragma unroll
            for (int nb = 0; nb < 16; nb++) {
                f16x8 b = *(const f16x8*)&b1t[(nb * 16 + lm) * 72 + ks * 32 + kg * 8];
                acc[nb] = __builtin_amdgcn_mfma_f32_16x16x32_f16(afrag[ks], b, acc[nb], 0, 0, 0);
            }

#pragma unroll
        for (int nb = 0; nb < 16; nb++) {
            int col = nb * 16 + lm;
            float bias = (col < 128) ? b1[col] : 0.0f;
#pragma unroll
            for (int reg = 0; reg < 4; reg++) {
                int orow = base + w * 16 + kg * 4 + reg;
                if (orow < N) PQ[(size_t)orow * 256 + col] = (f16)(acc[nb][reg] + bias);
            }
        }
        if (tid < 64) {
            int n = base + tid;
            if (n < N) {
                const float* xr = x + (size_t)n * 64;
                C[n] = make_float4(xr[0], xr[1], xr[2], 0.0f);
            }
        }
    }
}

// ---------------------------------------------------------------------------
// Edge kernel v10: q-only DMA staging + P[dst] VGPR-prefetched one tile ahead.
//   q (true random gather) staged via global_load_lds (16KB/block);
//   p = PQ[dcl] read directly per-lane (dst-sorted -> ~2 distinct rows/tile,
//   L1 same-line broadcast), issued in step 5 of iteration t-1 so its latency
//   hides behind GEMM2 + loop (R6's mistake was loading p at the wait point).
//   W2T in LDS (32KB XOR-swizzled); W3T global/L1; deferred-epilogue atomics.
// LDS 32+16+4.5 = 52.5KB -> 3 blocks/CU (12 waves, +50% vs R8).
// ---------------------------------------------------------------------------
__global__ __launch_bounds__(256, 3) void edge_kernel(
    const f16* __restrict__ PQ, const float4* __restrict__ C,
    const int2* __restrict__ sd,
    const f16* __restrict__ W2T, const f16* __restrict__ W3T,
    const f16* __restrict__ w1c, const float* __restrict__ b2,
    const float* __restrict__ b3, float* __restrict__ xout,
    int E, int wtiles) {
    __shared__ f16 w2t[128 * 128];       // 32KB XOR-swizzled
    __shared__ f16 stage[4 * 2048];      // 16KB: per-wave q (16 edges x 128 f16)
    __shared__ f16 tb[4 * 576];          // 4.5KB per-wave transpose slices

    const int tid = threadIdx.x;
    const int w = tid >> 6, lane = tid & 63, lm = lane & 15, kg = lane >> 4;
    const int e4 = lane >> 2, c4 = lane & 3;

    for (int i = tid; i < 128 * 128; i += 256) {
        int n = i >> 7, k = i & 127;
        w2t[n * 128 + (((k >> 3) ^ (n & 15)) << 3) + (k & 7)] = W2T[i];
    }

    // loop-invariant hoists
    f16x8 wvh[4];
#pragma unroll
    for (int ks = 0; ks < 4; ks++) wvh[ks] = *(const f16x8*)(w1c + ks * 32 + kg * 8);
    float bias2[8], bias3[4];
#pragma unroll
    for (int nb = 0; nb < 8; nb++) bias2[nb] = b2[nb * 16 + lm];
#pragma unroll
    for (int nb = 0; nb < 4; nb++) bias3[nb] = b3[nb * 16 + lm];
    __syncthreads();   // w2t ready; no barriers after this

    f16* sw = stage + w * 2048;          // this wave's q stage
    f16* tq = tb + w * 576;
    const int nwaves = gridDim.x * 4;
    const int r0 = kg * 4;
    const int l1i = (lane + 16) & 63, l2i = (lane + 32) & 63, l3i = (lane + 48) & 63;

    // ---- prologue: tile-0 idx, q-DMA, p-prefetch, C ----
    int t = blockIdx.x * 4 + w;
    if (t >= wtiles) return;
    int e0 = t * 16 + lm;
    int erc = min(e0, E - 1);
    int2 sd0 = sd[erc];
    int scl = sd0.x, dcl = sd0.y;
    int dsen_cur = (e0 < E) ? dcl : -1;
    {   // DMA-q(t)
        int se = __shfl(scl, e4);
        const f16* gq = PQ + (size_t)se * 256 + 128 + c4 * 8;
#pragma unroll
        for (int j = 0; j < 4; j++) load_lds16(gq + j * 32, sw + j * 512 + lane * 8);
    }
    // p(t): lane's own dcl row, direct (no shfl), L1 broadcast-hot
    f16x8 pv[4];
    {
        const f16* gp = PQ + (size_t)dcl * 256 + kg * 8;
#pragma unroll
        for (int ks = 0; ks < 4; ks++) pv[ks] = *(const f16x8*)(gp + ks * 32);
    }
    int e1 = (t + nwaves) * 16 + lm;
    int erc1 = min(max(e1, 0), E - 1);
    int2 sdn = sd[erc1];
    int s_nx = sdn.x, d_nx = sdn.y;
    int e_nx_ok = (e1 < E) ? 1 : 0;
    float4 cs = C[scl], cd = C[dcl];

    f32x4 acc2p[4];
#pragma unroll
    for (int nb2 = 0; nb2 < 4; nb2++) acc2p[nb2] = (f32x4){0.f, 0.f, 0.f, 0.f};
    int dsen_prev = -1;

    while (true) {
        const int tn = t + nwaves;

        // ---- 1. stage-q(t) + p/sd/C all issued >=1 iteration ago: drain ----
        asm volatile("s_waitcnt vmcnt(0)" ::: "memory");

        float dx = cs.x - cd.x, dy = cs.y - cd.y, dz = cs.z - cd.z;
        float dist2 = dx * dx + dy * dy + dz * dz;
        f16 d2h = (f16)dist2;

        // ---- 2. h1: packed f16 (pk_add/pk_fma + f16 silu) ----
        f16x8 afrag[4];
#pragma unroll
        for (int ks = 0; ks < 4; ks++) {
            f16x8 q = *(const f16x8*)&sw[ks * 512 + lm * 32 + kg * 8];
            f16x8 xv = pv[ks] + q + d2h * wvh[ks];
            afrag[ks] = silu_h8(xv);
        }

        // ---- GEMM1: h1 @ W2 ----
        f32x4 acc1[8];
#pragma unroll
        for (int nb = 0; nb < 8; nb++) acc1[nb] = (f32x4){0.f, 0.f, 0.f, 0.f};
#pragma unroll
        for (int ks = 0; ks < 4; ks++)
#pragma unroll
            for (int nb = 0; nb < 8; nb++) {
                int n = nb * 16 + lm;
                f16x8 b = *(const f16x8*)&w2t[n * 128 + (((ks * 4 + kg) ^ (n & 15)) << 3)];
                acc1[nb] = __builtin_amdgcn_mfma_f32_16x16x32_f16(afrag[ks], b, acc1[nb], 0, 0, 0);
            }

        // ---- 3. deferred epilogue for PREVIOUS tile (atomics precede DMA) ----
        {
            const int dr0 = __shfl(dsen_prev, r0);
            const int dr1 = __shfl(dsen_prev, r0 + 1);
            const int dr2 = __shfl(dsen_prev, r0 + 2);
            const int dr3 = __shfl(dsen_prev, r0 + 3);
            int prevv = __shfl(dsen_prev, (r0 - 1) & 63);
            if (kg == 0) prevv = -1234567;

            const bool e01 = dr0 == dr1, e12 = dr1 == dr2, e23 = dr2 == dr3;
            const bool c01 = e01, c02 = e01 && e12, c03 = c02 && e23;
            const bool c12 = e12, c13 = e12 && e23;
            const int fullI = c03 ? 1 : 0;

            const int tgt = dr3;
            const int dr0_1 = __shfl(dr0, l1i), fu1 = __shfl(fullI, l1i);
            const int dr0_2 = __shfl(dr0, l2i), fu2 = __shfl(fullI, l2i);
            const int dr0_3 = __shfl(dr0, l3i);
            const bool take1 = (kg <= 2) && (dr0_1 == tgt);
            const bool take2 = take1 && fu1 && (kg <= 1) && (dr0_2 == tgt);
            const bool take3 = take2 && fu2 && (kg == 0) && (dr0_3 == tgt);

            const bool h0 = (dr0 != prevv) && (dr0 >= 0);
            const bool h1f = (!e01) && (dr1 >= 0);
            const bool h2f = (!e12) && (dr2 >= 0);
            const bool h3f = (!e23) && (dr3 >= 0);

            float t0v[4], t1v[4], t2v[4], t3v[4];
#pragma unroll
            for (int nb2 = 0; nb2 < 4; nb2++) {
                const float bias = bias3[nb2];
                const float v0 = silu_f(acc2p[nb2][0] + bias);
                const float v1 = silu_f(acc2p[nb2][1] + bias);
                const float v2 = silu_f(acc2p[nb2][2] + bias);
                const float v3 = silu_f(acc2p[nb2][3] + bias);
                float lead = v0 + (c01 ? v1 : 0.f) + (c02 ? v2 : 0.f) + (c03 ? v3 : 0.f);
                float ext = 0.f;
                const float le1 = __shfl(lead, l1i);
                const float le2 = __shfl(lead, l2i);
                const float le3 = __shfl(lead, l3i);
                if (take1) ext += le1;
                if (take2) ext += le2;
                if (take3) ext += le3;
                t0v[nb2] = lead + (c03 ? ext : 0.f);
                t1v[nb2] = v1 + (c12 ? v2 : 0.f) + (c13 ? (v3 + ext) : 0.f);
                t2v[nb2] = v2 + (e23 ? (v3 + ext) : 0.f);
                t3v[nb2] = v3 + ext;
            }
            if (h0) {
                float* p = xout + (size_t)dr0 * 64 + lm;
#pragma unroll
                for (int nb2 = 0; nb2 < 4; nb2++) atomicAdd(p + nb2 * 16, t0v[nb2]);
            }
            if (h1f) {
                float* p = xout + (size_t)dr1 * 64 + lm;
#pragma unroll
                for (int nb2 = 0; nb2 < 4; nb2++) atomicAdd(p + nb2 * 16, t1v[nb2]);
            }
            if (h2f) {
                float* p = xout + (size_t)dr2 * 64 + lm;
#pragma unroll
                for (int nb2 = 0; nb2 < 4; nb2++) atomicAdd(p + nb2 * 16, t2v[nb2]);
            }
            if (h3f) {
                float* p = xout + (size_t)dr3 * 64 + lm;
#pragma unroll
                for (int nb2 = 0; nb2 < 4; nb2++) atomicAdd(p + nb2 * 16, t3v[nb2]);
            }
        }

        // ---- 4. DMA-q(t+nw) into stage (stage(t) reads already executed) ----
        int dsen_nx = e_nx_ok ? d_nx : -1;
        if (tn < wtiles) {
            int se = __shfl(s_nx, e4);
            const f16* gq = PQ + (size_t)se * 256 + 128 + c4 * 8;
#pragma unroll
            for (int j = 0; j < 4; j++) load_lds16(gq + j * 32, sw + j * 512 + lane * 8);
        }

        // ---- 5. p(t+nw) prefetch, sd(t+2nw), C(t+nw) ----
        f16x8 pv2[4];
        {
            const f16* gp2 = PQ + (size_t)d_nx * 256 + kg * 8;
#pragma unroll
            for (int ks = 0; ks < 4; ks++) pv2[ks] = *(const f16x8*)(gp2 + ks * 32);
        }
        int e2 = (tn + nwaves) * 16 + lm;
        int erc2 = min(max(e2, 0), E - 1);
        int2 sd2 = sd[erc2];
        int e_nx2_ok = (e2 < E) ? 1 : 0;
        float4 cs2 = C[s_nx], cd2 = C[d_nx];

        // ---- 6. GEMM2 in 4 k-quarters (W3T via global/L1) ----
        f32x4 acc2[4];
#pragma unroll
        for (int nb2 = 0; nb2 < 4; nb2++) acc2[nb2] = (f32x4){0.f, 0.f, 0.f, 0.f};
#pragma unroll
        for (int kq = 0; kq < 4; kq++) {
#pragma unroll
            for (int nn = 0; nn < 2; nn++) {
                int nb = kq * 2 + nn;
#pragma unroll
                for (int reg = 0; reg < 4; reg++)
                    tq[(kg * 4 + reg) * 36 + nn * 16 + lm] =
                        (f16)silu_f(acc1[nb][reg] + bias2[nb]);
            }
            f16x8 a2 = *(const f16x8*)&tq[lm * 36 + kg * 8];
#pragma unroll
            for (int nb2 = 0; nb2 < 4; nb2++) {
                f16x8 b = *(const f16x8*)(W3T + (size_t)(nb2 * 16 + lm) * 128 +
                                          kq * 32 + kg * 8);
                acc2[nb2] = __builtin_amdgcn_mfma_f32_16x16x32_f16(a2, b, acc2[nb2], 0, 0, 0);
            }
        }

        // ---- 7. rotate pipeline state ----
#pragma unroll
        for (int nb2 = 0; nb2 < 4; nb2++) acc2p[nb2] = acc2[nb2];
#pragma unroll
        for (int ks = 0; ks < 4; ks++) pv[ks] = pv2[ks];
        dsen_prev = dsen_cur;
        dsen_cur = dsen_nx;
        s_nx = sd2.x; d_nx = sd2.y; e_nx_ok = e_nx2_ok;
        cs = cs2; cd = cd2;
        t = tn;
        if (t >= wtiles) break;
    }

    // ---- final deferred epilogue ----
    {
        const int dr0 = __shfl(dsen_prev, r0);
        const int dr1 = __shfl(dsen_prev, r0 + 1);
        const int dr2 = __shfl(dsen_prev, r0 + 2);
        const int dr3 = __shfl(dsen_prev, r0 + 3);
        int prevv = __shfl(dsen_prev, (r0 - 1) & 63);
        if (kg == 0) prevv = -1234567;

        const bool e01 = dr0 == dr1, e12 = dr1 == dr2, e23 = dr2 == dr3;
        const bool c01 = e01, c02 = e01 && e12, c03 = c02 && e23;
        const bool c12 = e12, c13 = e12 && e23;
        const int fullI = c03 ? 1 : 0;

        const int tgt = dr3;
        const int dr0_1 = __shfl(dr0, l1i), fu1 = __shfl(fullI, l1i);
        const int dr0_2 = __shfl(dr0, l2i), fu2 = __shfl(fullI, l2i);
        const int dr0_3 = __shfl(dr0, l3i);
        const bool take1 = (kg <= 2) && (dr0_1 == tgt);
        const bool take2 = take1 && fu1 && (kg <= 1) && (dr0_2 == tgt);
        const bool take3 = take2 && fu2 && (kg == 0) && (dr0_3 == tgt);

        const bool h0 = (dr0 != prevv) && (dr0 >= 0);
        const bool h1f = (!e01) && (dr1 >= 0);
        const bool h2f = (!e12) && (dr2 >= 0);
        const bool h3f = (!e23) && (dr3 >= 0);

        float t0v[4], t1v[4], t2v[4], t3v[4];
#pragma unroll
        for (int nb2 = 0; nb2 < 4; nb2++) {
            const float bias = bias3[nb2];
            const float v0 = silu_f(acc2p[nb2][0] + bias);
            const float v1 = silu_f(acc2p[nb2][1] + bias);
            const float v2 = silu_f(acc2p[nb2][2] + bias);
            const float v3 = silu_f(acc2p[nb2][3] + bias);
            float lead = v0 + (c01 ? v1 : 0.f) + (c02 ? v2 : 0.f) + (c03 ? v3 : 0.f);
            float ext = 0.f;
            const float le1 = __shfl(lead, l1i);
            const float le2 = __shfl(lead, l2i);
            const float le3 = __shfl(lead, l3i);
            if (take1) ext += le1;
            if (take2) ext += le2;
            if (take3) ext += le3;
            t0v[nb2] = lead + (c03 ? ext : 0.f);
            t1v[nb2] = v1 + (c12 ? v2 : 0.f) + (c13 ? (v3 + ext) : 0.f);
            t2v[nb2] = v2 + (e23 ? (v3 + ext) : 0.f);
            t3v[nb2] = v3 + ext;
        }
        if (h0) {
            float* p = xout + (size_t)dr0 * 64 + lm;
#pragma unroll
            for (int nb2 = 0; nb2 < 4; nb2++) atomicAdd(p + nb2 * 16, t0v[nb2]);
        }
        if (h1f) {
            float* p = xout + (size_t)dr1 * 64 + lm;
#pragma unroll
            for (int nb2 = 0; nb2 < 4; nb2++) atomicAdd(p + nb2 * 16, t1v[nb2]);
        }
        if (h2f) {
            float* p = xout + (size_t)dr2 * 64 + lm;
#pragma unroll
            for (int nb2 = 0; nb2 < 4; nb2++) atomicAdd(p + nb2 * 16, t2v[nb2]);
        }
        if (h3f) {
            float* p = xout + (size_t)dr3 * 64 + lm;
#pragma unroll
            for (int nb2 = 0; nb2 < 4; nb2++) atomicAdd(p + nb2 * 16, t3v[nb2]);
        }
    }
    asm volatile("s_waitcnt vmcnt(0)" ::: "memory");
}

// ---------------------------------------------------------------------------
// Fused pooling + readout head: one block per graph.
// ---------------------------------------------------------------------------
__global__ void pool_head_kernel(const float* __restrict__ xf, const float* __restrict__ u,
                                 const float* __restrict__ LW1, const float* __restrict__ Lb1,
                                 const float* __restrict__ LW2, const float* __restrict__ Lb2,
                                 const float* __restrict__ LW3, const float* __restrict__ Lb3,
                                 float* __restrict__ out, int N, int G) {
    int g = blockIdx.x;
    int t = threadIdx.x;
    int ch = t & 63, sub = t >> 6;
    long long n0 = ((long long)g * N + G - 1) / G;
    long long n1 = ((long long)(g + 1) * N + G - 1) / G;
    float sm = 0.f, mx = -3.0e38f;
    for (long long n = n0 + sub; n < n1; n += 4) {
        float v = xf[n * 64 + ch];
        sm += v;
        mx = fmaxf(mx, v);
    }
    __shared__ float ssum[256], smax[256];
    __shared__ float pl[194];
    __shared__ float hl[64];
    ssum[t] = sm;
    smax[t] = mx;
    __syncthreads();
    if (sub == 0) {
        float a = ssum[ch] + ssum[64 + ch] + ssum[128 + ch] + ssum[192 + ch];
        float m = fmaxf(fmaxf(smax[ch], smax[64 + ch]), fmaxf(smax[128 + ch], smax[192 + ch]));
        float cnt = (float)(n1 - n0);
        pl[ch] = a;
        pl[64 + ch] = a / fmaxf(cnt, 1.f);
        pl[128 + ch] = m;
    }
    if (t == 0) {
        pl[192] = u[g * 2];
        pl[193] = u[g * 2 + 1];
    }
    __syncthreads();
    float a = 0.f;
    if (t < 64) {
        a = Lb1[t];
        for (int k = 0; k < 194; k++) a += pl[k] * LW1[k * 64 + t];
        a = a / (1.0f + __expf(-a));
        hl[t] = a;
    }
    __syncthreads();
    float b = 0.f;
    if (t < 64) {
        b = Lb2[t];
        for (int k = 0; k < 64; k++) b += hl[k] * LW2[k * 64 + t];
        b = b / (1.0f + __expf(-b));
    }
    __syncthreads();
    if (t < 64) hl[t] = b;
    __syncthreads();
    if (t < 2) {
        float c = Lb3[t];
        for (int k = 0; k < 64; k++) c += hl[k] * LW3[k * 2 + t];
        out[g * 2 + t] = c;
    }
}

// ---------------------------------------------------------------------------
extern "C" void kernel_launch(void* const* d_in, const int* in_sizes, int n_in,
                              void* d_out, int out_size, void* d_ws, size_t ws_size,
                              hipStream_t stream) {
    const float* x   = (const float*)d_in[0];
    const float* u   = (const float*)d_in[1];
    const int*   ei  = (const int*)d_in[2];
    const float* W1  = (const float*)d_in[4];
    const float* b1  = (const float*)d_in[5];
    const float* W2  = (const float*)d_in[6];
    const float* b2  = (const float*)d_in[7];
    const float* W3  = (const float*)d_in[8];
    const float* b3  = (const float*)d_in[9];
    const float* LW1 = (const float*)d_in[10];
    const float* Lb1 = (const float*)d_in[11];
    const float* LW2 = (const float*)d_in[12];
    const float* Lb2 = (const float*)d_in[13];
    const float* LW3 = (const float*)d_in[14];
    const float* Lb3 = (const float*)d_in[15];

    const int N = in_sizes[0] / 64;
    const int G = in_sizes[1] / 2;
    const int E = in_sizes[2] / 2;
    const int L = in_sizes[4] / (126 * 128);

    char* ws = (char*)d_ws;
    size_t off = 0;
    auto alloc = [&](size_t bytes) -> char* {
        char* p = ws + off;
        off += (bytes + 511) & ~(size_t)511;
        return p;
    };
    f16*    PQ     = (f16*)alloc((size_t)N * 256 * 2);
    float4* C      = (float4*)alloc((size_t)N * 16);
    float*  x1     = (float*)alloc((size_t)N * 64 * 4);
    float*  x2     = (float*)alloc((size_t)N * 64 * 4);
    int2*   sd     = (int2*)alloc((size_t)E * 8);
    int*    deg    = (int*)alloc((size_t)N * 4);
    int*    rowst  = (int*)alloc((size_t)N * 4);
    int*    cursor = (int*)alloc((size_t)N * 4);
    int*    bsum   = (int*)alloc(4096);
    int*    boff   = (int*)alloc(4096);
    f16*    B1T    = (f16*)alloc((size_t)L * 256 * 64 * 2);
    f16*    W2T    = (f16*)alloc((size_t)L * 128 * 128 * 2);
    f16*    W3T    = (f16*)alloc((size_t)L * 64 * 128 * 2);
    f16*    w1c    = (f16*)alloc((size_t)L * 128 * 2);
    (void)ws_size;
    (void)n_in;
    (void)out_size;

    hipMemsetAsync(deg, 0, (size_t)N * 4, stream);
    hipMemsetAsync(cursor, 0, (size_t)N * 4, stream);
    hipMemsetAsync(x1, 0, (size_t)N * 64 * 4, stream);
    hipMemsetAsync(x2, 0, (size_t)N * 64 * 4, stream);

    {
        int total = L * (16384 + 16384 + 8192 + 128);
        prep_kernel<<<(total + 255) / 256, 256, 0, stream>>>(W1, W2, W3, B1T, W2T, W3T, w1c, L, total);
    }
    hist_kernel<<<(E + 255) / 256, 256, 0, stream>>>(ei, deg, E);
    int NB = (N + 255) / 256;
    scan_part<<<NB, 256, 0, stream>>>(deg, bsum, N);
    scan_mid<<<1, 512, 0, stream>>>(bsum, boff, NB);
    scan_final<<<NB, 256, 0, stream>>>(deg, boff, rowst, N);
    scatter_kernel<<<(E + 255) / 256, 256, 0, stream>>>(ei, rowst, cursor, sd, E);

    const float* xcur = x;
    const int wtiles = (E + 15) / 16;
    const int ntiles_node = (N + 63) / 64;
    for (int l = 0; l < L; l++) {
        node_kernel<<<768, 256, 0, stream>>>(xcur, B1T + (size_t)l * 16384, b1 + l * 128,
                                             PQ, C, N, ntiles_node);
        float* xo = (l & 1) ? x2 : x1;
        edge_kernel<<<768, 256, 0, stream>>>(PQ, C, sd,
                                             W2T + (size_t)l * 16384, W3T + (size_t)l * 8192,
                                             w1c + l * 128, b2 + l * 128, b3 + l * 64,
                                             xo, E, wtiles);
        xcur = xo;
    }
    pool_head_kernel<<<G, 256, 0, stream>>>(xcur, u, LW1, Lb1, LW2, Lb2, LW3, Lb3,
                                            (float*)d_out, N, G);
}